// Round 1
// baseline (181.729 us; speedup 1.0000x reference)
//
#include <hip/hip_runtime.h>

// TT embedding gather, vocab 125000 = 50*50*50, emb 512 = 8*8*8.
// cores: c1 (50,1,8,32) -> g1[m][r]; c2 (50,32,8,32) -> g2[r][n][s]; c3 (50,32,8,1) -> g3[s][p]
// out[m,n,p] = sum_{r,s} g1[m,r] g2[r,n,s] g3[s,p]
// Precompute T[i2*50+i3][r][n][p] = sum_s g2[r,n,s] g3[s,p]  (2500 pairs x 2048 floats per table)

#define NFAC 50
#define T_ELEMS_PER_PAIR 2048            // 32*8*8
#define NPAIRS 2500
#define NWORD 8192
#define NCTX  81920                      // 8192*10

__global__ __launch_bounds__(256) void tt_precompute(
    const float* __restrict__ core2,     // (50,32,8,32)
    const float* __restrict__ core3,     // (50,32,8)
    float* __restrict__ T)               // (2500,32,8,8)
{
    const int pair = blockIdx.x;                 // 0..2499
    const int i2 = pair / NFAC, i3 = pair % NFAC;
    __shared__ float g3s[256];                   // g3[s][p], s major
    const int t = threadIdx.x;
    g3s[t] = core3[i3 * 256 + t];
    __syncthreads();
    const int r = t >> 3, n = t & 7;
    const float* g2row = core2 + i2 * 8192 + r * 256 + n * 32;   // 32 consecutive floats
    float acc[8] = {0.f,0.f,0.f,0.f,0.f,0.f,0.f,0.f};
    #pragma unroll
    for (int s4 = 0; s4 < 8; ++s4) {
        const float4 v = reinterpret_cast<const float4*>(g2row)[s4];
        const float vv[4] = {v.x, v.y, v.z, v.w};
        #pragma unroll
        for (int j = 0; j < 4; ++j) {
            const int s = s4 * 4 + j;
            #pragma unroll
            for (int p = 0; p < 8; ++p)
                acc[p] += vv[j] * g3s[s * 8 + p];    // LDS broadcast (uniform addr)
        }
    }
    float* dst = T + (size_t)pair * T_ELEMS_PER_PAIR + t * 8;
    reinterpret_cast<float4*>(dst)[0] = make_float4(acc[0], acc[1], acc[2], acc[3]);
    reinterpret_cast<float4*>(dst)[1] = make_float4(acc[4], acc[5], acc[6], acc[7]);
}

// One block (512 threads) per lookup: out = g1 (8x32) @ T (32x64)
__global__ __launch_bounds__(512) void tt_lookup(
    const int* __restrict__ word_idx,    // 8192
    const int* __restrict__ ctx_idx,     // 81920
    const float* __restrict__ w_core1, const float* __restrict__ c_core1,
    const float* __restrict__ Tw, const float* __restrict__ Tc,
    float* __restrict__ out)
{
    const int b = blockIdx.x;
    int idx; const float* core1; const float* T; float* o;
    if (b < NWORD) {
        idx = word_idx[b]; core1 = w_core1; T = Tw;
        o = out + (size_t)b * 512;
    } else {
        const int c = b - NWORD;
        idx = ctx_idx[c]; core1 = c_core1; T = Tc;
        o = out + (size_t)(NWORD + c) * 512;
    }
    const int i3 = idx % NFAC;
    const int rem = idx / NFAC;
    const int i2 = rem % NFAC;
    const int i1 = rem / NFAC;

    __shared__ float Ts[T_ELEMS_PER_PAIR];   // [r][np]
    __shared__ float g1s[256];               // [m][r]
    const int t = threadIdx.x;
    const float* Tsrc = T + (size_t)(i2 * NFAC + i3) * T_ELEMS_PER_PAIR;
    reinterpret_cast<float4*>(Ts)[t] = reinterpret_cast<const float4*>(Tsrc)[t];
    if (t < 64)
        reinterpret_cast<float4*>(g1s)[t] = reinterpret_cast<const float4*>(core1 + i1 * 256)[t];
    __syncthreads();

    const int m = t >> 6;          // wave-uniform
    const int np = t & 63;         // lane id
    const float* g1r = g1s + m * 32;
    float acc = 0.f;
    #pragma unroll
    for (int r = 0; r < 32; ++r)
        acc += g1r[r] * Ts[r * 64 + np];   // g1: broadcast; Ts: lane-consecutive (conflict-free)
    o[m * 64 + np] = acc;
}

// Fallback (ws too small): fuse T computation into the lookup block.
__global__ __launch_bounds__(512) void tt_fused(
    const int* __restrict__ word_idx, const int* __restrict__ ctx_idx,
    const float* __restrict__ w1, const float* __restrict__ w2, const float* __restrict__ w3,
    const float* __restrict__ c1, const float* __restrict__ c2, const float* __restrict__ c3,
    float* __restrict__ out)
{
    const int b = blockIdx.x;
    int idx; const float *k1, *k2, *k3; float* o;
    if (b < NWORD) { idx = word_idx[b]; k1 = w1; k2 = w2; k3 = w3; o = out + (size_t)b * 512; }
    else { const int c = b - NWORD; idx = ctx_idx[c]; k1 = c1; k2 = c2; k3 = c3;
           o = out + (size_t)(NWORD + c) * 512; }
    const int i3 = idx % NFAC;
    const int rem = idx / NFAC;
    const int i2 = rem % NFAC;
    const int i1 = rem / NFAC;

    __shared__ float g3s[256];
    __shared__ float g1s[256];
    __shared__ float Ts[T_ELEMS_PER_PAIR];
    const int t = threadIdx.x;
    if (t < 256) g3s[t] = k3[i3 * 256 + t];
    else         g1s[t - 256] = k1[i1 * 256 + (t - 256)];
    __syncthreads();

    {   // phase 1: T[r][n][p], 4 consecutive elems per thread
        const int e0 = t * 4;
        const int r = e0 >> 6, n = (e0 >> 3) & 7, p0 = e0 & 7;   // p0 in {0,4}
        const float* g2row = k2 + i2 * 8192 + r * 256 + n * 32;
        float acc[4] = {0.f,0.f,0.f,0.f};
        #pragma unroll
        for (int s = 0; s < 32; ++s) {
            const float v = g2row[s];
            #pragma unroll
            for (int j = 0; j < 4; ++j) acc[j] += v * g3s[s * 8 + p0 + j];
        }
        reinterpret_cast<float4*>(Ts + e0)[0] = make_float4(acc[0], acc[1], acc[2], acc[3]);
    }
    __syncthreads();

    const int m = t >> 6, np = t & 63;
    float acc = 0.f;
    #pragma unroll
    for (int r = 0; r < 32; ++r)
        acc += g1s[m * 32 + r] * Ts[r * 64 + np];
    o[m * 64 + np] = acc;
}

extern "C" void kernel_launch(void* const* d_in, const int* in_sizes, int n_in,
                              void* d_out, int out_size, void* d_ws, size_t ws_size,
                              hipStream_t stream) {
    const int*   widx = (const int*)d_in[0];
    const int*   cidx = (const int*)d_in[1];
    const float* w1   = (const float*)d_in[2];
    const float* w2   = (const float*)d_in[3];
    const float* w3   = (const float*)d_in[4];
    const float* c1   = (const float*)d_in[5];
    const float* c2   = (const float*)d_in[6];
    const float* c3   = (const float*)d_in[7];
    float* out = (float*)d_out;

    const size_t t_elems = (size_t)NPAIRS * T_ELEMS_PER_PAIR;
    if (ws_size >= 2 * t_elems * sizeof(float)) {
        float* Tw = (float*)d_ws;
        float* Tc = Tw + t_elems;
        tt_precompute<<<NPAIRS, 256, 0, stream>>>(w2, w3, Tw);
        tt_precompute<<<NPAIRS, 256, 0, stream>>>(c2, c3, Tc);
        tt_lookup<<<NWORD + NCTX, 512, 0, stream>>>(widx, cidx, w1, c1, Tw, Tc, out);
    } else {
        tt_fused<<<NWORD + NCTX, 512, 0, stream>>>(widx, cidx, w1, w2, w3, c1, c2, c3, out);
    }
}

// Round 3
// 140.582 us; speedup vs baseline: 1.2927x; 1.2927x over previous
//
#include <hip/hip_runtime.h>

// TT embedding gather, vocab 125000 = 50*50*50, emb 512 = 8*8*8.
// c1 (50,1,8,32) -> g1[m][r]; c2 (50,32,8,32) -> g2[r][n][s]; c3 (50,32,8,1) -> g3[s][p]
// out[m,n,p] = sum_{r,s} g1[m,r] g2[r,n,s] g3[s,p]
// Stage 1: T[i2*50+i3][r][np] = sum_s g2[r,n,s] g3[s,p]   (2500 pairs x 2048 floats, per table)
// Stage 2: 1 wave per lookup, lane=np: t[r]=T[r][np] in VGPRs (coalesced dword loads),
//          g1 rows via s_load_dwordx16 into SGPRs (readfirstlane-uniformed base),
//          inner loop = pure v_fmac_f32 (sgpr x vgpr). No LDS, no barriers.

#define NFAC 50
#define TPAIR 2048
#define NPAIRS 2500
#define NWORD 8192
#define NCTX  81920
#define NLOOK (NWORD + NCTX)

typedef float f16v __attribute__((ext_vector_type(16)));

// Wave-uniform pointer -> SGPR pair (compiler can't prove uniformity of
// per-wave branchy selects; readfirstlane forces it).
__device__ __forceinline__ const float* uptr(const float* p) {
    unsigned long long v = (unsigned long long)p;
    unsigned lo = __builtin_amdgcn_readfirstlane((unsigned)v);
    unsigned hi = __builtin_amdgcn_readfirstlane((unsigned)(v >> 32));
    return (const float*)(((unsigned long long)hi << 32) | lo);
}

__global__ __launch_bounds__(256) void tt_precompute(
    const float* __restrict__ w2, const float* __restrict__ w3,
    const float* __restrict__ c2, const float* __restrict__ c3,
    float* __restrict__ Tw, float* __restrict__ Tc)
{
    int pair = blockIdx.x;
    const float* core2; const float* core3; float* T;
    if (pair < NPAIRS) { core2 = w2; core3 = w3; T = Tw; }
    else { pair -= NPAIRS; core2 = c2; core3 = c3; T = Tc; }
    const int i2 = pair / NFAC, i3 = pair % NFAC;
    __shared__ float g3s[256];                   // g3[s][p], s major
    const int t = threadIdx.x;
    g3s[t] = core3[i3 * 256 + t];
    __syncthreads();
    const int r = t >> 3, n = t & 7;
    const float* g2row = core2 + i2 * 8192 + r * 256 + n * 32;   // 32 consecutive floats
    float acc[8] = {0.f,0.f,0.f,0.f,0.f,0.f,0.f,0.f};
    #pragma unroll
    for (int s4 = 0; s4 < 8; ++s4) {
        const float4 v = reinterpret_cast<const float4*>(g2row)[s4];
        const float vv[4] = {v.x, v.y, v.z, v.w};
        #pragma unroll
        for (int j = 0; j < 4; ++j) {
            const int s = s4 * 4 + j;
            #pragma unroll
            for (int p = 0; p < 8; ++p)
                acc[p] += vv[j] * g3s[s * 8 + p];    // LDS broadcast (uniform addr)
        }
    }
    float* dst = T + (size_t)pair * TPAIR + t * 8;   // [r][n][p] = [r][np]
    reinterpret_cast<float4*>(dst)[0] = make_float4(acc[0], acc[1], acc[2], acc[3]);
    reinterpret_cast<float4*>(dst)[1] = make_float4(acc[4], acc[5], acc[6], acc[7]);
}

// 1 wave = 1 lookup. 256-thread blocks carry 4 independent waves. Zero LDS.
__global__ __launch_bounds__(256, 8) void tt_lookup(
    const int* __restrict__ word_idx,    // 8192
    const int* __restrict__ ctx_idx,     // 81920
    const float* __restrict__ w_core1, const float* __restrict__ c_core1,
    const float* __restrict__ Tw, const float* __restrict__ Tc,
    float* __restrict__ out)
{
    const int wave = threadIdx.x >> 6;
    const int lane = threadIdx.x & 63;
    const int look = blockIdx.x * 4 + wave;          // NWORD%4==0: no wave straddles tables

    int vidx; const float* core1; const float* T;
    if (look < NWORD) { vidx = word_idx[look]; core1 = w_core1; T = Tw; }
    else              { vidx = ctx_idx[look - NWORD]; core1 = c_core1; T = Tc; }
    const int idx = __builtin_amdgcn_readfirstlane(vidx);
    const int i3  = idx % NFAC;
    const int rem = idx / NFAC;
    const int i2  = rem % NFAC;
    const int i1  = rem / NFAC;

    // Wave-uniform SGPR bases.
    const float* Ts  = uptr(T + (size_t)(i2 * NFAC + i3) * TPAIR);
    const float* g1p = uptr(core1 + i1 * 256);

    // T column for this lane: 32 coalesced dword loads (256 B per wave-instr), all in flight.
    float t[32];
    #pragma unroll
    for (int r = 0; r < 32; ++r) t[r] = Ts[r * 64 + lane];

    float* o = out + (size_t)look * 512 + lane;

    #pragma unroll
    for (int mp = 0; mp < 4; ++mp) {                 // two m-rows (64 g1 floats) per iter
        f16v g0, g1, g2, g3;
        asm volatile(
            "s_load_dwordx16 %0, %4, %5\n\t"
            "s_load_dwordx16 %1, %4, %6\n\t"
            "s_load_dwordx16 %2, %4, %7\n\t"
            "s_load_dwordx16 %3, %4, %8"
            : "=&s"(g0), "=&s"(g1), "=&s"(g2), "=&s"(g3)
            : "s"(g1p), "i"(mp * 256), "i"(mp * 256 + 64),
              "i"(mp * 256 + 128), "i"(mp * 256 + 192));
        // Wait carries the loaded values so dependent FMAs cannot hoist above it.
        asm volatile("s_waitcnt lgkmcnt(0)"
                     : "+s"(g0), "+s"(g1), "+s"(g2), "+s"(g3));
        float a0 = 0.f, b0 = 0.f, a1 = 0.f, b1 = 0.f;   // 4 independent FMA chains
        #pragma unroll
        for (int r = 0; r < 16; ++r) {
            a0 += g0[r] * t[r];
            b0 += g1[r] * t[16 + r];
            a1 += g2[r] * t[r];
            b1 += g3[r] * t[16 + r];
        }
        o[(2 * mp)     * 64] = a0 + b0;
        o[(2 * mp + 1) * 64] = a1 + b1;
    }
}

// Fallback (ws too small): fuse T computation into the lookup block.
__global__ __launch_bounds__(512) void tt_fused(
    const int* __restrict__ word_idx, const int* __restrict__ ctx_idx,
    const float* __restrict__ w1, const float* __restrict__ w2, const float* __restrict__ w3,
    const float* __restrict__ c1, const float* __restrict__ c2, const float* __restrict__ c3,
    float* __restrict__ out)
{
    const int b = blockIdx.x;
    int idx; const float *k1, *k2, *k3; float* o;
    if (b < NWORD) { idx = word_idx[b]; k1 = w1; k2 = w2; k3 = w3; o = out + (size_t)b * 512; }
    else { const int c = b - NWORD; idx = ctx_idx[c]; k1 = c1; k2 = c2; k3 = c3;
           o = out + (size_t)(NWORD + c) * 512; }
    const int i3 = idx % NFAC;
    const int rem = idx / NFAC;
    const int i2 = rem % NFAC;
    const int i1 = rem / NFAC;

    __shared__ float g3s[256];
    __shared__ float g1s[256];
    __shared__ float Ts[TPAIR];
    const int t = threadIdx.x;
    if (t < 256) g3s[t] = k3[i3 * 256 + t];
    else         g1s[t - 256] = k1[i1 * 256 + (t - 256)];
    __syncthreads();

    {   // phase 1: T[r][n][p], 4 consecutive elems per thread
        const int e0 = t * 4;
        const int r = e0 >> 6, n = (e0 >> 3) & 7, p0 = e0 & 7;
        const float* g2row = k2 + i2 * 8192 + r * 256 + n * 32;
        float acc[4] = {0.f,0.f,0.f,0.f};
        #pragma unroll
        for (int s = 0; s < 32; ++s) {
            const float v = g2row[s];
            #pragma unroll
            for (int j = 0; j < 4; ++j) acc[j] += v * g3s[s * 8 + p0 + j];
        }
        reinterpret_cast<float4*>(Ts + e0)[0] = make_float4(acc[0], acc[1], acc[2], acc[3]);
    }
    __syncthreads();

    const int m = t >> 6, np = t & 63;
    float acc = 0.f;
    #pragma unroll
    for (int r = 0; r < 32; ++r)
        acc += g1s[m * 32 + r] * Ts[r * 64 + np];
    o[m * 64 + np] = acc;
}

extern "C" void kernel_launch(void* const* d_in, const int* in_sizes, int n_in,
                              void* d_out, int out_size, void* d_ws, size_t ws_size,
                              hipStream_t stream) {
    const int*   widx = (const int*)d_in[0];
    const int*   cidx = (const int*)d_in[1];
    const float* w1   = (const float*)d_in[2];
    const float* w2   = (const float*)d_in[3];
    const float* w3   = (const float*)d_in[4];
    const float* c1   = (const float*)d_in[5];
    const float* c2   = (const float*)d_in[6];
    const float* c3   = (const float*)d_in[7];
    float* out = (float*)d_out;

    const size_t t_elems = (size_t)NPAIRS * TPAIR;
    if (ws_size >= 2 * t_elems * sizeof(float)) {
        float* Tw = (float*)d_ws;
        float* Tc = Tw + t_elems;
        tt_precompute<<<2 * NPAIRS, 256, 0, stream>>>(w2, w3, c2, c3, Tw, Tc);
        tt_lookup<<<NLOOK / 4, 256, 0, stream>>>(widx, cidx, w1, c1, Tw, Tc, out);
    } else {
        tt_fused<<<NLOOK, 512, 0, stream>>>(widx, cidx, w1, w2, w3, c1, c2, c3, out);
    }
}